// Round 16
// baseline (31.350 us; speedup 1.0000x reference)
//
#include <hip/hip_runtime.h>
#include <math.h>

// Problem constants (B=4, S=2048, D=1024, C=10)
constexpr int D_DIM = 1024;
constexpr int C_DIM = 10;
constexpr int WPB   = 8;            // waves (tokens) per block
constexpr int BLOCK = 64 * WPB;     // 512 threads

constexpr float CLAMP_V  = 1.0e6f;
constexpr float LOG2E    = 1.4426950408889634f;
constexpr float LN2      = 0.6931471805599453f;
constexpr float INV_2PI  = 0.15915494309189535f;

// native 2-wide float vector -> backend emits v_pk_{fma,mul,add}_f32 (VOP3P)
using v2 = __attribute__((ext_vector_type(2))) float;

__device__ __forceinline__ v2 mkv2(float a, float b) { v2 r; r.x = a; r.y = b; return r; }

#if __has_builtin(__builtin_amdgcn_fractf)
#define FRACT(v) __builtin_amdgcn_fractf(v)
#else
#define FRACT(v) ((v) - rintf(v))
#endif

// wave-uniform value -> SGPR
__device__ __forceinline__ float rfl(float x) {
    return __int_as_float(__builtin_amdgcn_readfirstlane(__float_as_int(x)));
}

// ---- DPP wave64 sum -> SGPR (full-rate VALU, no LDS pipe) ----
template <int CTRL>
__device__ __forceinline__ float dpp_add(float v) {
    const int s = __builtin_amdgcn_update_dpp(
        0, __float_as_int(v), CTRL, 0xf, 0xf, false);
    return v + __int_as_float(s);
}
__device__ __forceinline__ float wave_sum_sgpr(float v) {
    v = dpp_add<0x111>(v);   // row_shr:1
    v = dpp_add<0x112>(v);   // row_shr:2
    v = dpp_add<0x114>(v);   // row_shr:4
    v = dpp_add<0x118>(v);   // row_shr:8
    v = dpp_add<0x142>(v);   // row_bcast:15
    v = dpp_add<0x143>(v);   // row_bcast:31 -> lane 63 = total
    return __int_as_float(__builtin_amdgcn_readlane(__float_as_int(v), 63));
}

// ======= prep kernel: grid-constant derived scale constants -> d_ws ========
// cst layout: [0]a0 [1]a1 [2]k2 [3]o2 [4]k3 [5]o3 [6]k4 [7]o4 [8]v5 [9]a6
//             [10]k7 [11]o7 [12]k8 [13]o8 [14]k9 [15]o9 [16]m9
__global__ __launch_bounds__(64)
void prep_kernel(const float* __restrict__ log_in_scale,
                 const float* __restrict__ log_out_scale,
                 float* __restrict__ cst)
{
    if (threadIdx.x != 0) return;
    float in_s[C_DIM], out_s[C_DIM];
#pragma unroll
    for (int c = 0; c < C_DIM; ++c) {
        in_s[c]  = __builtin_amdgcn_exp2f(log_in_scale[c]  * LOG2E);
        out_s[c] = __builtin_amdgcn_exp2f(log_out_scale[c] * LOG2E);
    }
    cst[0]  = out_s[0] * in_s[0];
    cst[1]  = out_s[1] * in_s[1] * in_s[1];
    cst[2]  = in_s[2];            cst[3]  = out_s[2];
    cst[4]  = in_s[3] * INV_2PI;  cst[5]  = out_s[3];
    cst[6]  = in_s[4] * LOG2E;    cst[7]  = out_s[4];
    cst[8]  = fminf(out_s[5], CLAMP_V);
    cst[9]  = out_s[6] * in_s[6] * in_s[6] * in_s[6];
    cst[10] = in_s[7];            cst[11] = out_s[7] * LN2;
    cst[12] = in_s[8];            cst[13] = out_s[8];
    cst[14] = 2.0f * in_s[9] * LOG2E;
    cst[15] = out_s[9];           cst[16] = -2.0f * out_s[9];
}

__global__ __launch_bounds__(BLOCK)   // natural allocation (forcing spills: r5/r7)
void fused_sme_kernel(const float* __restrict__ x,
                      const float* __restrict__ ln_gamma,
                      const float* __restrict__ ln_beta,
                      const float* __restrict__ cst,      // 17 derived consts
                      const float* __restrict__ gate_w,
                      const float* __restrict__ gate_b,
                      float* __restrict__ out_weighted,   // (tokens, D)
                      float* __restrict__ out_gate,       // (tokens, C)
                      int tokens)
{
    const int t    = threadIdx.x;
    const int lane = t & 63;
    const int wv   = t >> 6;
    const int token = blockIdx.x * WPB + wv;   // grid divides exactly (8192/8)

    __shared__ float gws[C_DIM * D_DIM];    // 40 KB: whole gate_w per block

    // ---- this wave's 16 x-elements as 8 v2 pairs: d = k*256 + lane*4 ----
    const float* xrow = x + (size_t)token * D_DIM + (lane << 2);
    v2 xp[8];
#pragma unroll
    for (int k = 0; k < 4; ++k) {
        const float4 f = *reinterpret_cast<const float4*>(xrow + k * 256);
        xp[2 * k]     = mkv2(f.x, f.y);
        xp[2 * k + 1] = mkv2(f.z, f.w);
    }

    // ---- cooperative gate_w stage: 2560 float4 over 512 threads ----
#pragma unroll
    for (int i = 0; i < 5; ++i) {
        const int idx = t + i * BLOCK;
        reinterpret_cast<float4*>(gws)[idx] =
            reinterpret_cast<const float4*>(gate_w)[idx];
    }

    // ---- derived constants: uniform address -> scalar loads (SGPR) ----
    const float a0 = cst[0],  a1 = cst[1];
    const float k2 = cst[2],  o2 = cst[3];
    const float k3 = cst[4],  o3 = cst[5];
    const float k4 = cst[6],  o4 = cst[7];
    const float v5 = cst[8],  a6 = cst[9];
    const float k7 = cst[10], o7 = cst[11];
    const float k8 = cst[12], o8 = cst[13];
    const float k9 = cst[14], o9 = cst[15], m9 = cst[16];

    // ---- LN partials (packed; overlap with staging latency) ----
    float r[12];
    {
        v2 s = {0.f, 0.f}, q = {0.f, 0.f};
#pragma unroll
        for (int p = 0; p < 8; ++p) {
            s += xp[p];
            q = xp[p] * xp[p] + q;
        }
        r[0] = wave_sum_sgpr(s.x + s.y);
        r[1] = wave_sum_sgpr(q.x + q.y);
    }

    __syncthreads();      // #1: gate_w resident in LDS

    // ---- gate dots from LDS (ds_read_b128; packed fma) ----
#pragma unroll
    for (int c = 0; c < C_DIM; ++c) {
        const float* gr = gws + c * D_DIM + (lane << 2);
        v2 d2 = {0.f, 0.f};
#pragma unroll
        for (int k = 0; k < 4; ++k) {
            const float4 g = *reinterpret_cast<const float4*>(gr + k * 256);
            d2 = xp[2 * k]     * mkv2(g.x, g.y) + d2;
            d2 = xp[2 * k + 1] * mkv2(g.z, g.w) + d2;
        }
        r[2 + c] = wave_sum_sgpr(d2.x + d2.y);
    }

    // ---- input LayerNorm stats (SGPR) ----
    const float mu   = r[0] * (1.0f / D_DIM);
    const float var  = r[1] * (1.0f / D_DIM) - mu * mu;
    const float rstd = rfl(rsqrtf(var + 1e-5f));

    // ---- gate softmax (wave-uniform) ----
    float w[C_DIM];
    float gmax = -3.4e38f;
#pragma unroll
    for (int c = 0; c < C_DIM; ++c) {
        w[c] = r[2 + c] + gate_b[c];
        gmax = fmaxf(gmax, w[c]);
    }
    float esum = 0.0f;
#pragma unroll
    for (int c = 0; c < C_DIM; ++c) {
        w[c] = __builtin_amdgcn_exp2f((w[c] - gmax) * LOG2E);
        esum += w[c];
    }
    const float rsum = __builtin_amdgcn_rcpf(esum);
#pragma unroll
    for (int c = 0; c < C_DIM; ++c) w[c] = rfl(w[c] * rsum);

    // gate output store early: overlaps with the candidate pass
    if (lane < C_DIM) out_gate[token * C_DIM + lane] = w[lane];

    // ---- normalized x overwrites xp in place (packed) ----
#pragma unroll
    for (int k = 0; k < 4; ++k) {
        const float4 gv = *reinterpret_cast<const float4*>(ln_gamma + k * 256 + (lane << 2));
        const float4 bv = *reinterpret_cast<const float4*>(ln_beta  + k * 256 + (lane << 2));
        xp[2 * k]     = ((xp[2 * k]     - mu) * rstd) * mkv2(gv.x, gv.y) + mkv2(bv.x, bv.y);
        xp[2 * k + 1] = ((xp[2 * k + 1] - mu) * rstd) * mkv2(gv.z, gv.w) + mkv2(bv.z, bv.w);
    }

    // ---- candidate pass: joint-LN stats + gated accumulation (VOP3P packed,
    // SGPR constants). weighted = (sum_c w_c*cand_c - mu2)*rsig; post-LN
    // clip/nan dead; sum w = 1; c5 hoisted. acc overwrites xp in place. ----
    const float accbase = rfl(w[5] * v5);
    v2 S1 = {0.f, 0.f}, S2 = {0.f, 0.f};

#pragma unroll
    for (int p = 0; p < 8; ++p) {
        const v2 xj = xp[p];
        const v2 ax = mkv2(fabsf(xj.x), fabsf(xj.y));
        const v2 x2 = xj * xj;

        const v2 v0 = a0 * xj;
        const v2 v1 = a1 * x2;

        const v2 u2 = k2 * xj;          // cos period 1 in revolutions: fract ok
        const v2 vc2 = o2 * mkv2(__builtin_amdgcn_cosf(FRACT(u2.x)),
                                 __builtin_amdgcn_cosf(FRACT(u2.y)));

        const v2 u3 = k3 * xj;
        const v2 vc3 = o3 * mkv2(__builtin_amdgcn_sinf(FRACT(u3.x)),
                                 __builtin_amdgcn_sinf(FRACT(u3.y)));

        const v2 u4 = k4 * xj;
        const v2 e4 = o4 * mkv2(__builtin_amdgcn_exp2f(u4.x),
                                __builtin_amdgcn_exp2f(u4.y));
        const v2 vc4 = mkv2(fminf(e4.x, CLAMP_V), fminf(e4.y, CLAMP_V));

        const v2 v6 = a6 * (x2 * xj);

        const v2 u7 = k7 * ax + 1.0f;
        const v2 vc7 = o7 * mkv2(__builtin_amdgcn_logf(u7.x),
                                 __builtin_amdgcn_logf(u7.y));

        const v2 u8 = k8 * ax;
        const v2 vc8 = o8 * mkv2(__builtin_amdgcn_sqrtf(u8.x),
                                 __builtin_amdgcn_sqrtf(u8.y));

        const v2 u9 = k9 * xj;
        const v2 vc9 = m9 * mkv2(
            __builtin_amdgcn_rcpf(__builtin_amdgcn_exp2f(u9.x) + 1.0f),
            __builtin_amdgcn_rcpf(__builtin_amdgcn_exp2f(u9.y) + 1.0f)) + o9;

        S1 += ((v0 + v1) + (vc2 + vc3)) + ((vc4 + v6) + (vc7 + vc8)) + vc9;
        S2 = v0 * v0 + S2;  S2 = v1 * v1 + S2;  S2 = vc2 * vc2 + S2;
        S2 = vc3 * vc3 + S2; S2 = vc4 * vc4 + S2; S2 = v6 * v6 + S2;
        S2 = vc7 * vc7 + S2; S2 = vc8 * vc8 + S2; S2 = vc9 * vc9 + S2;

        v2 a = mkv2(accbase, accbase);
        a = w[0] * v0 + a;  a = w[1] * v1 + a;  a = w[2] * vc2 + a;
        a = w[3] * vc3 + a; a = w[4] * vc4 + a; a = w[6] * v6 + a;
        a = w[7] * vc7 + a; a = w[8] * vc8 + a; a = w[9] * vc9 + a;
        xp[p] = a;                 // in-place: xp[p] now holds acc
    }

    // c5 stats contribution (16 elements per lane)
    const float s1 = wave_sum_sgpr(S1.x + S1.y + 16.0f * v5);
    const float s2 = wave_sum_sgpr(fmaf(16.0f * v5, v5, S2.x + S2.y));

    constexpr float rn = 1.0f / (float)(C_DIM * D_DIM);
    const float mu2  = s1 * rn;
    const float var2 = s2 * rn - mu2 * mu2;
    const float rsig = rfl(rsqrtf(var2 + 1e-5f));

    // ---- write outputs (packed epilogue) ----
    float* orow = out_weighted + (size_t)token * D_DIM + (lane << 2);
#pragma unroll
    for (int k = 0; k < 4; ++k) {
        const v2 lo = (xp[2 * k]     - mu2) * rsig;
        const v2 hi = (xp[2 * k + 1] - mu2) * rsig;
        float4 o;
        o.x = lo.x; o.y = lo.y; o.z = hi.x; o.w = hi.y;
        *reinterpret_cast<float4*>(orow + k * 256) = o;
    }
}

extern "C" void kernel_launch(void* const* d_in, const int* in_sizes, int n_in,
                              void* d_out, int out_size, void* d_ws, size_t ws_size,
                              hipStream_t stream) {
    const float* x   = (const float*)d_in[0];
    const float* lg  = (const float*)d_in[1];
    const float* lb  = (const float*)d_in[2];
    const float* lis = (const float*)d_in[3];
    const float* los = (const float*)d_in[4];
    const float* gw  = (const float*)d_in[5];
    const float* gb  = (const float*)d_in[6];

    const int tokens = in_sizes[0] / D_DIM;   // B*S = 8192
    float* out      = (float*)d_out;
    float* out_gate = out + (size_t)tokens * D_DIM;
    float* cst      = (float*)d_ws;           // 17 derived constants

    hipLaunchKernelGGL(prep_kernel, dim3(1), dim3(64), 0, stream,
                       lis, los, cst);

    const int grid = (tokens + WPB - 1) / WPB;
    hipLaunchKernelGGL(fused_sme_kernel, dim3(grid), dim3(BLOCK), 0, stream,
                       x, lg, lb, cst, gw, gb, out, out_gate, tokens);
}

// Round 17
// 27.895 us; speedup vs baseline: 1.1239x; 1.1239x over previous
//
#include <hip/hip_runtime.h>
#include <math.h>

// Problem constants (B=4, S=2048, D=1024, C=10)
constexpr int D_DIM = 1024;
constexpr int C_DIM = 10;
constexpr int WPB   = 8;            // waves (tokens) per block
constexpr int BLOCK = 64 * WPB;     // 512 threads

constexpr float CLAMP_V  = 1.0e6f;
constexpr float LOG2E    = 1.4426950408889634f;
constexpr float LN2      = 0.6931471805599453f;
constexpr float INV_2PI  = 0.15915494309189535f;

// native 2-wide float vector -> backend emits v_pk_{fma,mul,add}_f32 (VOP3P)
using v2 = __attribute__((ext_vector_type(2))) float;

__device__ __forceinline__ v2 mkv2(float a, float b) { v2 r; r.x = a; r.y = b; return r; }

#if __has_builtin(__builtin_amdgcn_fractf)
#define FRACT(v) __builtin_amdgcn_fractf(v)
#else
#define FRACT(v) ((v) - rintf(v))
#endif

// wave-uniform value -> SGPR
__device__ __forceinline__ float rfl(float x) {
    return __int_as_float(__builtin_amdgcn_readfirstlane(__float_as_int(x)));
}

// ---- DPP wave64 sum -> SGPR (full-rate VALU, no LDS pipe) ----
template <int CTRL>
__device__ __forceinline__ float dpp_add(float v) {
    const int s = __builtin_amdgcn_update_dpp(
        0, __float_as_int(v), CTRL, 0xf, 0xf, false);
    return v + __int_as_float(s);
}
__device__ __forceinline__ float wave_sum_sgpr(float v) {
    v = dpp_add<0x111>(v);   // row_shr:1
    v = dpp_add<0x112>(v);   // row_shr:2
    v = dpp_add<0x114>(v);   // row_shr:4
    v = dpp_add<0x118>(v);   // row_shr:8
    v = dpp_add<0x142>(v);   // row_bcast:15
    v = dpp_add<0x143>(v);   // row_bcast:31 -> lane 63 = total
    return __int_as_float(__builtin_amdgcn_readlane(__float_as_int(v), 63));
}

__global__ __launch_bounds__(BLOCK)   // natural allocation (forcing spills: r5/r7)
void fused_sme_kernel(const float* __restrict__ x,
                      const float* __restrict__ ln_gamma,
                      const float* __restrict__ ln_beta,
                      const float* __restrict__ log_in_scale,
                      const float* __restrict__ log_out_scale,
                      const float* __restrict__ gate_w,
                      const float* __restrict__ gate_b,
                      float* __restrict__ out_weighted,   // (tokens, D)
                      float* __restrict__ out_gate,       // (tokens, C)
                      int tokens)
{
    const int t    = threadIdx.x;
    const int lane = t & 63;
    const int wv   = t >> 6;
    const int token = blockIdx.x * WPB + wv;   // grid divides exactly (8192/8)

    __shared__ float gws[C_DIM * D_DIM];    // 40 KB: whole gate_w per block

    // ---- async gate_w stage: global_load_lds (no VGPR round-trip) ----
    // HW writes LDS at (wave-uniform base) + lane*16; source is per-lane.
#pragma unroll
    for (int i = 0; i < 5; ++i) {
        const int base = (wv << 6) + (i << 9);           // float4 idx, wave-uniform
        __builtin_amdgcn_global_load_lds(
            (const __attribute__((address_space(1))) unsigned int*)
                (gate_w + ((size_t)(base + lane) << 2)),
            (__attribute__((address_space(3))) unsigned int*)
                (gws + ((size_t)base << 2)),
            16, 0, 0);
    }

    // ---- this wave's 16 x-elements as 8 v2 pairs: d = k*256 + lane*4 ----
    const float* xrow = x + (size_t)token * D_DIM + (lane << 2);
    v2 xp[8];
#pragma unroll
    for (int k = 0; k < 4; ++k) {
        const float4 f = *reinterpret_cast<const float4*>(xrow + k * 256);
        xp[2 * k]     = mkv2(f.x, f.y);
        xp[2 * k + 1] = mkv2(f.z, f.w);
    }

    // ---- LN partials (packed; overlap with staging latency) ----
    float r[12];
    {
        v2 s = {0.f, 0.f}, q = {0.f, 0.f};
#pragma unroll
        for (int p = 0; p < 8; ++p) {
            s += xp[p];
            q = xp[p] * xp[p] + q;
        }
        r[0] = wave_sum_sgpr(s.x + s.y);
        r[1] = wave_sum_sgpr(q.x + q.y);
    }

    __syncthreads();      // #1: drains global_load_lds -> gate_w resident

    // ---- gate dots from LDS (ds_read_b128; packed fma) ----
#pragma unroll
    for (int c = 0; c < C_DIM; ++c) {
        const float* gr = gws + c * D_DIM + (lane << 2);
        v2 d2 = {0.f, 0.f};
#pragma unroll
        for (int k = 0; k < 4; ++k) {
            const float4 g = *reinterpret_cast<const float4*>(gr + k * 256);
            d2 = xp[2 * k]     * mkv2(g.x, g.y) + d2;
            d2 = xp[2 * k + 1] * mkv2(g.z, g.w) + d2;
        }
        r[2 + c] = wave_sum_sgpr(d2.x + d2.y);
    }

    // ---- input LayerNorm stats (SGPR) ----
    const float mu   = r[0] * (1.0f / D_DIM);
    const float var  = r[1] * (1.0f / D_DIM) - mu * mu;
    const float rstd = rfl(rsqrtf(var + 1e-5f));

    // ---- gate softmax (wave-uniform) ----
    float w[C_DIM];
    float gmax = -3.4e38f;
#pragma unroll
    for (int c = 0; c < C_DIM; ++c) {
        w[c] = r[2 + c] + gate_b[c];
        gmax = fmaxf(gmax, w[c]);
    }
    float esum = 0.0f;
#pragma unroll
    for (int c = 0; c < C_DIM; ++c) {
        w[c] = __builtin_amdgcn_exp2f((w[c] - gmax) * LOG2E);
        esum += w[c];
    }
    const float rsum = __builtin_amdgcn_rcpf(esum);
#pragma unroll
    for (int c = 0; c < C_DIM; ++c) w[c] = rfl(w[c] * rsum);

    // gate output store early: overlaps with the candidate pass
    if (lane < C_DIM) out_gate[token * C_DIM + lane] = w[lane];

    // ---- scales (grid-uniform; one-time; SGPR via rfl) ----
    float in_s[C_DIM], out_s[C_DIM];
#pragma unroll
    for (int c = 0; c < C_DIM; ++c) {
        in_s[c]  = __builtin_amdgcn_exp2f(log_in_scale[c]  * LOG2E);
        out_s[c] = __builtin_amdgcn_exp2f(log_out_scale[c] * LOG2E);
    }
    // derived constants; |xn| <= ~42 => only exp's output clamp can fire
    const float a0 = rfl(out_s[0] * in_s[0]);
    const float a1 = rfl(out_s[1] * in_s[1] * in_s[1]);
    const float k2 = rfl(in_s[2]),           o2 = rfl(out_s[2]);
    const float k3 = rfl(in_s[3] * INV_2PI), o3 = rfl(out_s[3]);
    const float k4 = rfl(in_s[4] * LOG2E),   o4 = rfl(out_s[4]);
    const float v5 = rfl(fminf(out_s[5], CLAMP_V));
    const float a6 = rfl(out_s[6] * in_s[6] * in_s[6] * in_s[6]);
    const float k7 = rfl(in_s[7]),           o7 = rfl(out_s[7] * LN2);
    const float k8 = rfl(in_s[8]),           o8 = rfl(out_s[8]);
    const float k9 = rfl(2.0f * in_s[9] * LOG2E);
    const float o9 = rfl(out_s[9]),          m9 = rfl(-2.0f * out_s[9]);

    // ---- normalized x overwrites xp in place (packed) ----
#pragma unroll
    for (int k = 0; k < 4; ++k) {
        const float4 gv = *reinterpret_cast<const float4*>(ln_gamma + k * 256 + (lane << 2));
        const float4 bv = *reinterpret_cast<const float4*>(ln_beta  + k * 256 + (lane << 2));
        xp[2 * k]     = ((xp[2 * k]     - mu) * rstd) * mkv2(gv.x, gv.y) + mkv2(bv.x, bv.y);
        xp[2 * k + 1] = ((xp[2 * k + 1] - mu) * rstd) * mkv2(gv.z, gv.w) + mkv2(bv.z, bv.w);
    }

    // ---- candidate pass: joint-LN stats + gated accumulation (VOP3P packed,
    // SGPR constants). weighted = (sum_c w_c*cand_c - mu2)*rsig; post-LN
    // clip/nan dead; sum w = 1; c5 hoisted. acc overwrites xp in place. ----
    const float accbase = rfl(w[5] * v5);
    v2 S1 = {0.f, 0.f}, S2 = {0.f, 0.f};

#pragma unroll
    for (int p = 0; p < 8; ++p) {
        const v2 xj = xp[p];
        const v2 ax = mkv2(fabsf(xj.x), fabsf(xj.y));
        const v2 x2 = xj * xj;

        const v2 v0 = a0 * xj;
        const v2 v1 = a1 * x2;

        const v2 u2 = k2 * xj;          // cos period 1 in revolutions: fract ok
        const v2 vc2 = o2 * mkv2(__builtin_amdgcn_cosf(FRACT(u2.x)),
                                 __builtin_amdgcn_cosf(FRACT(u2.y)));

        const v2 u3 = k3 * xj;
        const v2 vc3 = o3 * mkv2(__builtin_amdgcn_sinf(FRACT(u3.x)),
                                 __builtin_amdgcn_sinf(FRACT(u3.y)));

        const v2 u4 = k4 * xj;
        const v2 e4 = o4 * mkv2(__builtin_amdgcn_exp2f(u4.x),
                                __builtin_amdgcn_exp2f(u4.y));
        const v2 vc4 = mkv2(fminf(e4.x, CLAMP_V), fminf(e4.y, CLAMP_V));

        const v2 v6 = a6 * (x2 * xj);

        const v2 u7 = k7 * ax + 1.0f;
        const v2 vc7 = o7 * mkv2(__builtin_amdgcn_logf(u7.x),
                                 __builtin_amdgcn_logf(u7.y));

        const v2 u8 = k8 * ax;
        const v2 vc8 = o8 * mkv2(__builtin_amdgcn_sqrtf(u8.x),
                                 __builtin_amdgcn_sqrtf(u8.y));

        const v2 u9 = k9 * xj;
        const v2 vc9 = m9 * mkv2(
            __builtin_amdgcn_rcpf(__builtin_amdgcn_exp2f(u9.x) + 1.0f),
            __builtin_amdgcn_rcpf(__builtin_amdgcn_exp2f(u9.y) + 1.0f)) + o9;

        S1 += ((v0 + v1) + (vc2 + vc3)) + ((vc4 + v6) + (vc7 + vc8)) + vc9;
        S2 = v0 * v0 + S2;  S2 = v1 * v1 + S2;  S2 = vc2 * vc2 + S2;
        S2 = vc3 * vc3 + S2; S2 = vc4 * vc4 + S2; S2 = v6 * v6 + S2;
        S2 = vc7 * vc7 + S2; S2 = vc8 * vc8 + S2; S2 = vc9 * vc9 + S2;

        v2 a = mkv2(accbase, accbase);
        a = w[0] * v0 + a;  a = w[1] * v1 + a;  a = w[2] * vc2 + a;
        a = w[3] * vc3 + a; a = w[4] * vc4 + a; a = w[6] * v6 + a;
        a = w[7] * vc7 + a; a = w[8] * vc8 + a; a = w[9] * vc9 + a;
        xp[p] = a;                 // in-place: xp[p] now holds acc
    }

    // c5 stats contribution (16 elements per lane)
    const float s1 = wave_sum_sgpr(S1.x + S1.y + 16.0f * v5);
    const float s2 = wave_sum_sgpr(fmaf(16.0f * v5, v5, S2.x + S2.y));

    constexpr float rn = 1.0f / (float)(C_DIM * D_DIM);
    const float mu2  = s1 * rn;
    const float var2 = s2 * rn - mu2 * mu2;
    const float rsig = rfl(rsqrtf(var2 + 1e-5f));

    // ---- write outputs (packed epilogue) ----
    float* orow = out_weighted + (size_t)token * D_DIM + (lane << 2);
#pragma unroll
    for (int k = 0; k < 4; ++k) {
        const v2 lo = (xp[2 * k]     - mu2) * rsig;
        const v2 hi = (xp[2 * k + 1] - mu2) * rsig;
        float4 o;
        o.x = lo.x; o.y = lo.y; o.z = hi.x; o.w = hi.y;
        *reinterpret_cast<float4*>(orow + k * 256) = o;
    }
}

extern "C" void kernel_launch(void* const* d_in, const int* in_sizes, int n_in,
                              void* d_out, int out_size, void* d_ws, size_t ws_size,
                              hipStream_t stream) {
    const float* x   = (const float*)d_in[0];
    const float* lg  = (const float*)d_in[1];
    const float* lb  = (const float*)d_in[2];
    const float* lis = (const float*)d_in[3];
    const float* los = (const float*)d_in[4];
    const float* gw  = (const float*)d_in[5];
    const float* gb  = (const float*)d_in[6];

    const int tokens = in_sizes[0] / D_DIM;   // B*S = 8192
    float* out      = (float*)d_out;
    float* out_gate = out + (size_t)tokens * D_DIM;

    const int grid = (tokens + WPB - 1) / WPB;
    hipLaunchKernelGGL(fused_sme_kernel, dim3(grid), dim3(BLOCK), 0, stream,
                       x, lg, lb, lis, los, gw, gb, out, out_gate, tokens);
}